// Round 14
// baseline (253.688 us; speedup 1.0000x reference)
//
#include <hip/hip_runtime.h>
#include <math.h>

#define NPTS 8192
#define NB   4
#define KNN  16
#define NC   64
#define NQ   (NB * NPTS)   // 32768 total queries
#define CAP2 32            // per-(wave,query) LDS survivor capacity (E~5.5)
#define CAP2P 34           // padded stride (bank spread for select reads)

// ---------------------------------------------------------------------------
// prep (2 phases as separate blocks) — unchanged (validated r2..r13):
//  phase 0 (source pts): cand[b][m]=(x,y,z,|p|^2); GF[b][m][o]=(Gk,F2)
//  phase 1 (center pts): CF[b][n][o]=(Gc+bg, F1+bf)
// ---------------------------------------------------------------------------
__global__ __launch_bounds__(256) void prep_kernel(
    const float* __restrict__ xyz, const float* __restrict__ xyz_s,
    const float* __restrict__ fea, const float* __restrict__ fea_s,
    const float* __restrict__ Wg,  const float* __restrict__ bg,
    const float* __restrict__ Wf,  const float* __restrict__ bf,
    float4* __restrict__ cand, float2* __restrict__ GF, float2* __restrict__ CF)
{
    __shared__ float wt[64 * 64];
    __shared__ float gw[3 * 64];
    __shared__ float bias2[2 * 64];
    int tid   = threadIdx.x;
    int phase = blockIdx.x & 1;
    int g     = (blockIdx.x >> 1) * 256 + tid;
    int b     = g >> 13, m = g & (NPTS - 1);

    for (int i = tid; i < 4096; i += 256) {
        int o = i >> 6, c = i & 63;
        wt[c * 64 + o] = Wf[o * 128 + (phase ? c : 64 + c)];
    }
    if (tid < 192) {
        int d = tid >> 6, o = tid & 63;
        gw[d * 64 + o] = phase ? (Wg[o * 10 + 1 + d] + Wg[o * 10 + 7 + d])
                               : (Wg[o * 10 + 4 + d] - Wg[o * 10 + 7 + d]);
    }
    if (tid < 64) {
        bias2[tid]      = phase ? bg[tid] : 0.f;
        bias2[64 + tid] = phase ? bf[tid] : 0.f;
    }
    __syncthreads();

    const float* P = phase ? xyz : xyz_s;
    const float* F = phase ? fea : fea_s;
    float x = P[(b * 3 + 0) * NPTS + m];
    float y = P[(b * 3 + 1) * NPTS + m];
    float z = P[(b * 3 + 2) * NPTS + m];
    if (!phase) cand[b * NPTS + m] = make_float4(x, y, z, x * x + y * y + z * z);

    float acc[NC];
    #pragma unroll
    for (int o = 0; o < NC; o++) acc[o] = 0.f;
    for (int c = 0; c < NC; c++) {
        float v = F[(size_t)(b * NC + c) * NPTS + m];
        const float4* w4 = (const float4*)&wt[c * 64];
        #pragma unroll
        for (int o4 = 0; o4 < 16; o4++) {
            float4 w = w4[o4];
            acc[o4*4+0] = fmaf(w.x, v, acc[o4*4+0]);
            acc[o4*4+1] = fmaf(w.y, v, acc[o4*4+1]);
            acc[o4*4+2] = fmaf(w.z, v, acc[o4*4+2]);
            acc[o4*4+3] = fmaf(w.w, v, acc[o4*4+3]);
        }
    }
    float2* O = (phase ? CF : GF) + ((size_t)(b * NPTS + m)) * NC;
    #pragma unroll
    for (int o = 0; o < NC; o++) {
        float geo = fmaf(gw[o], x, fmaf(gw[64 + o], y, gw[128 + o] * z));
        O[o] = make_float2(geo + bias2[o], acc[o] + bias2[64 + o]);
    }
}

// ---------------------------------------------------------------------------
// knn_fused2: tau + filter + select in ONE candidate-stationary kernel.
// [r13 post-mortem: VGPR=84 < 128 needed for c[32] — compiler re-loaded
//  candidates from L2 inside both query loops; at 2 waves/SIMD those stalls
//  gave VALUBusy 44% / 161us. Since waves/SIMD is quantized (halves at VGPR
//  128/256) and our 512-block grid supplies exactly 2 waves/SIMD anyway,
//  __launch_bounds__(256,2) frees the allocator to keep c[32] RESIDENT at
//  zero occupancy cost. Pass A now uses dual max accumulators (fmax exactly
//  associative -> tau bit-identical).]
// Block = 4 waves; wave w holds candidates [2048w,2048(w+1)) in registers,
// lane l owns 32 contiguous (c[32]); 64 queries/block from 1KB LDS table.
//  A: per-lane max (2 chains) -> shfl_xor(1,2,4) 8-lane reduce -> 32
//     sub-chunk maxima (256 cands each) covering all 8192.
//  T: tau = 16th largest of 32 maxima (r9-validated bitonic) -> >=16
//     witnesses guaranteed.
//  B: re-score (bit-identical fma), ballot-prefix push to wave-private LDS.
//  S: thread-per-query u64 sorted-insert -> idxb. Grid: NQ/64 = 512.
// ---------------------------------------------------------------------------
__global__ __launch_bounds__(256, 2) void knn_fused2(
    const float4* __restrict__ cand, const float* __restrict__ xyz,
    int* __restrict__ idxout)
{
    __shared__ float4 qt_lds[64];
    __shared__ float  mxs[64][33];
    __shared__ float  tauL[64];
    __shared__ unsigned short wl[4][64][CAP2P];
    __shared__ unsigned char  wcnt[4][64];

    int tid = threadIdx.x;
    int lane = tid & 63, w = tid >> 6;
    int bid = blockIdx.x;
    int b = bid >> 7;                      // 128 blocks per batch
    int qb = (bid & 127) * 64;

    if (tid < 64) {
        int q = qb + tid;
        float x = xyz[(b * 3 + 0) * NPTS + q];
        float y = xyz[(b * 3 + 1) * NPTS + q];
        float z = xyz[(b * 3 + 2) * NPTS + q];
        qt_lds[tid] = make_float4(2.f * x, 2.f * y, 2.f * z, 0.f);
    }

    const float4* cb = cand + b * NPTS;
    int cbase = (w << 11) + (lane << 5);   // this lane's 32 contiguous cands
    float4 c[32];
    #pragma unroll
    for (int s = 0; s < 32; s++) c[s] = cb[cbase + s];
    __syncthreads();

    // ---- A: sub-chunk maxima (dual-chain lane max + 8-lane reduce) ----
    for (int qi = 0; qi < 64; ++qi) {
        float4 qt = qt_lds[qi];
        float M0 = -3.0e38f, M1 = -3.0e38f;
        #pragma unroll
        for (int s = 0; s < 32; s += 2) {
            float sc0 = fmaf(c[s].x, qt.x, fmaf(c[s].y, qt.y,
                        fmaf(c[s].z, qt.z, -c[s].w)));
            float sc1 = fmaf(c[s+1].x, qt.x, fmaf(c[s+1].y, qt.y,
                        fmaf(c[s+1].z, qt.z, -c[s+1].w)));
            M0 = fmaxf(M0, sc0);
            M1 = fmaxf(M1, sc1);
        }
        float gmx = fmaxf(M0, M1);
        gmx = fmaxf(gmx, __shfl_xor(gmx, 1));
        gmx = fmaxf(gmx, __shfl_xor(gmx, 2));
        gmx = fmaxf(gmx, __shfl_xor(gmx, 4));   // 8-lane group max
        if ((lane & 7) == 0) mxs[qi][(w << 3) + (lane >> 3)] = gmx;
    }
    __syncthreads();

    // ---- T: tau = 16th largest of 32 sub-chunk maxima (bitonic, r9 form) --
    for (int qq = w * 16; qq < w * 16 + 16; ++qq) {
        float v = (lane < 32) ? mxs[qq][lane] : -3.0e38f;
        #pragma unroll
        for (int k = 2; k <= 64; k <<= 1) {
            #pragma unroll
            for (int j = k >> 1; j > 0; j >>= 1) {
                float o = __shfl_xor(v, j);
                bool up = ((lane & k) == 0);
                bool lower = ((lane & j) == 0);
                v = (up == lower) ? fminf(v, o) : fmaxf(v, o);
            }
        }
        float t = __shfl(v, 48);           // 16th largest (all lanes execute)
        if (lane == 0) tauL[qq] = t;
    }
    __syncthreads();

    // ---- B: filter with ballot-prefix push (zero atomics) ----
    unsigned long long lmask = (1ull << lane) - 1ull;
    for (int qi = 0; qi < 64; ++qi) {
        float4 qt = qt_lds[qi];
        float tau = tauL[qi];
        unsigned vcnt = 0;
        #pragma unroll
        for (int s = 0; s < 32; s++) {
            float sc = fmaf(c[s].x, qt.x, fmaf(c[s].y, qt.y,
                       fmaf(c[s].z, qt.z, -c[s].w)));
            bool p = (sc >= tau);
            unsigned long long mask = __ballot(p);
            if (p) {
                unsigned pos = vcnt + (unsigned)__popcll(mask & lmask);
                if (pos < CAP2)
                    wl[w][qi][pos] = (unsigned short)(cbase + s);
            }
            vcnt += (unsigned)__popcll(mask);
        }
        if (lane == 0)
            wcnt[w][qi] = (unsigned char)(vcnt < CAP2 ? vcnt : CAP2);
    }
    __syncthreads();

    // ---- S: thread-per-query top-16 select (r7/r12-validated insert) ----
    if (tid < 64) {
        int qi = tid;
        float4 qt = qt_lds[qi];
        unsigned long long s16[KNN];
        #pragma unroll
        for (int j = 0; j < KNN; j++) s16[j] = 0ull;

        for (int cgp = 0; cgp < 4; cgp++) {
            int cn = wcnt[cgp][qi];
            for (int j0 = 0; j0 < cn; j0 += 4) {
                int li[4];
                float4 cd[4];
                #pragma unroll
                for (int t = 0; t < 4; t++) {
                    int j = j0 + t;
                    li[t] = (j < cn) ? (int)wl[cgp][qi][j] : -1;
                }
                #pragma unroll
                for (int t = 0; t < 4; t++)
                    if (li[t] >= 0) cd[t] = cb[li[t]];
                #pragma unroll
                for (int t = 0; t < 4; t++) {
                    if (li[t] < 0) continue;
                    float sc = fmaf(cd[t].x, qt.x, fmaf(cd[t].y, qt.y,
                               fmaf(cd[t].z, qt.z, -cd[t].w)));
                    unsigned u = __float_as_uint(sc);
                    u ^= (unsigned)((int)u >> 31) | 0x80000000u;
                    unsigned long long key =
                        ((unsigned long long)u << 32) | (unsigned)(8191 - li[t]);
                    if (key > s16[0]) {
                        bool cj = true;
                        #pragma unroll
                        for (int t2 = 0; t2 < KNN; t2++) {
                            bool cn2 = (t2 < KNN - 1) ? (key > s16[t2 + 1]) : false;
                            unsigned long long fv = cj ? key : s16[t2];
                            s16[t2] = cn2 ? s16[t2 + 1] : fv;
                            cj = cn2;
                        }
                    }
                }
            }
        }
        int* op = idxout + (((size_t)(b * NPTS + qb + qi)) << 4);
        #pragma unroll
        for (int j = 0; j < KNN; j++)
            op[j] = 8191 - (int)(s16[j] & 0xFFFFFFFFull);
    }
}

// ---------------------------------------------------------------------------
// fuse — unchanged (validated r2..r13):
// out[b][o][n] = max_k relu(CF.x + wd*d + GF.x) * relu(CF.y + GF.y)
// ---------------------------------------------------------------------------
__global__ __launch_bounds__(256) void fuse_kernel(
    const float* __restrict__ xyz, const float* __restrict__ Wg,
    const float4* __restrict__ cand, const float2* __restrict__ GF,
    const float2* __restrict__ CF, const int* __restrict__ idxb,
    float* __restrict__ out)
{
    __shared__ float tile[16 * 65];
    int tid = threadIdx.x;
    int o = tid & 63, w = tid >> 6;
    int b = blockIdx.x >> 9;
    int nt = (blockIdx.x & 511) << 4;
    float wd = Wg[o * 10];

    for (int i = 0; i < 4; i++) {
        int q = nt + w * 4 + i;
        size_t qb = (size_t)(b * NPTS + q);
        float qx = xyz[(b * 3 + 0) * NPTS + q];
        float qy = xyz[(b * 3 + 1) * NPTS + q];
        float qz = xyz[(b * 3 + 2) * NPTS + q];
        float2 cf = CF[qb * NC + o];
        const int* ip = idxb + qb * KNN;
        float r = 0.f;
        #pragma unroll 4
        for (int kk = 0; kk < KNN; kk++) {
            int mi = ip[kk];
            float4 c = cand[b * NPTS + mi];
            float dx = qx - c.x, dy = qy - c.y, dz = qz - c.z;
            float d = sqrtf(fmaf(dx, dx, fmaf(dy, dy, dz * dz)));
            float2 gf = GF[((size_t)(b * NPTS + mi)) * NC + o];
            float gpre = cf.x + fmaf(wd, d, gf.x);
            float fpre = cf.y + gf.y;
            r = fmaxf(r, fmaxf(gpre, 0.f) * fmaxf(fpre, 0.f));
        }
        tile[(w * 4 + i) * 65 + o] = r;
    }
    __syncthreads();
    int row = tid >> 2, cg = (tid & 3) * 4;
    float* orow = out + (size_t)(b * NC + row) * NPTS + nt + cg;
    #pragma unroll
    for (int j = 0; j < 4; j++) orow[j] = tile[(cg + j) * 65 + row];
}

extern "C" void kernel_launch(void* const* d_in, const int* in_sizes, int n_in,
                              void* d_out, int out_size, void* d_ws, size_t ws_size,
                              hipStream_t stream) {
    const float* xyz   = (const float*)d_in[0];
    const float* xyz_s = (const float*)d_in[1];
    const float* fea   = (const float*)d_in[2];
    const float* fea_s = (const float*)d_in[3];
    const float* Wg    = (const float*)d_in[4];
    const float* bg    = (const float*)d_in[5];
    const float* Wf    = (const float*)d_in[6];
    const float* bf    = (const float*)d_in[7];
    float* out = (float*)d_out;

    char* ws = (char*)d_ws;
    float4* cand = (float4*)ws;                 ws += (size_t)NQ * 16;      // 512 KB
    float2* GF   = (float2*)ws;                 ws += (size_t)NQ * NC * 8;  // 16.8 MB
    float2* CF   = (float2*)ws;                 ws += (size_t)NQ * NC * 8;  // 16.8 MB
    int*    idxb = (int*)ws;                                                // 2 MB

    prep_kernel<<<(NQ / 256) * 2, 256, 0, stream>>>(
        xyz, xyz_s, fea, fea_s, Wg, bg, Wf, bf, cand, GF, CF);
    knn_fused2<<<NQ / 64, 256, 0, stream>>>(cand, xyz, idxb);
    fuse_kernel<<<NB * (NPTS / 16), 256, 0, stream>>>(
        xyz, Wg, cand, GF, CF, idxb, out);
}

// Round 15
// 207.497 us; speedup vs baseline: 1.2226x; 1.2226x over previous
//
#include <hip/hip_runtime.h>
#include <math.h>

#define NPTS 8192
#define NB   4
#define KNN  16
#define NC   64
#define NQ   (NB * NPTS)   // 32768 total queries
#define CAP3 24            // per-(wave,query) LDS survivor capacity (E~2.5)
#define CAP3P 26           // padded stride

// ---------------------------------------------------------------------------
// prep (2 phases as separate blocks) — unchanged (validated r2..r14):
//  phase 0 (source pts): cand[b][m]=(x,y,z,|p|^2); GF[b][m][o]=(Gk,F2)
//  phase 1 (center pts): CF[b][n][o]=(Gc+bg, F1+bf)
// ---------------------------------------------------------------------------
__global__ __launch_bounds__(256) void prep_kernel(
    const float* __restrict__ xyz, const float* __restrict__ xyz_s,
    const float* __restrict__ fea, const float* __restrict__ fea_s,
    const float* __restrict__ Wg,  const float* __restrict__ bg,
    const float* __restrict__ Wf,  const float* __restrict__ bf,
    float4* __restrict__ cand, float2* __restrict__ GF, float2* __restrict__ CF)
{
    __shared__ float wt[64 * 64];
    __shared__ float gw[3 * 64];
    __shared__ float bias2[2 * 64];
    int tid   = threadIdx.x;
    int phase = blockIdx.x & 1;
    int g     = (blockIdx.x >> 1) * 256 + tid;
    int b     = g >> 13, m = g & (NPTS - 1);

    for (int i = tid; i < 4096; i += 256) {
        int o = i >> 6, c = i & 63;
        wt[c * 64 + o] = Wf[o * 128 + (phase ? c : 64 + c)];
    }
    if (tid < 192) {
        int d = tid >> 6, o = tid & 63;
        gw[d * 64 + o] = phase ? (Wg[o * 10 + 1 + d] + Wg[o * 10 + 7 + d])
                               : (Wg[o * 10 + 4 + d] - Wg[o * 10 + 7 + d]);
    }
    if (tid < 64) {
        bias2[tid]      = phase ? bg[tid] : 0.f;
        bias2[64 + tid] = phase ? bf[tid] : 0.f;
    }
    __syncthreads();

    const float* P = phase ? xyz : xyz_s;
    const float* F = phase ? fea : fea_s;
    float x = P[(b * 3 + 0) * NPTS + m];
    float y = P[(b * 3 + 1) * NPTS + m];
    float z = P[(b * 3 + 2) * NPTS + m];
    if (!phase) cand[b * NPTS + m] = make_float4(x, y, z, x * x + y * y + z * z);

    float acc[NC];
    #pragma unroll
    for (int o = 0; o < NC; o++) acc[o] = 0.f;
    for (int c = 0; c < NC; c++) {
        float v = F[(size_t)(b * NC + c) * NPTS + m];
        const float4* w4 = (const float4*)&wt[c * 64];
        #pragma unroll
        for (int o4 = 0; o4 < 16; o4++) {
            float4 w = w4[o4];
            acc[o4*4+0] = fmaf(w.x, v, acc[o4*4+0]);
            acc[o4*4+1] = fmaf(w.y, v, acc[o4*4+1]);
            acc[o4*4+2] = fmaf(w.z, v, acc[o4*4+2]);
            acc[o4*4+3] = fmaf(w.w, v, acc[o4*4+3]);
        }
    }
    float2* O = (phase ? CF : GF) + ((size_t)(b * NPTS + m)) * NC;
    #pragma unroll
    for (int o = 0; o < NC; o++) {
        float geo = fmaf(gw[o], x, fmaf(gw[64 + o], y, gw[128 + o] * z));
        O[o] = make_float2(geo + bias2[o], acc[o] + bias2[64 + o]);
    }
}

// ---------------------------------------------------------------------------
// knn_fused3: tau + filter + select, candidate-stationary, 8 waves/block.
// [r14 post-mortem: launch_bounds(256,2) left VGPR=84 — allocator refused to
//  hold c[32] (128 regs) and re-loaded candidates in both passes at 2
//  waves/SIMD. Fix: (1) c[16]/lane (64 regs) with 8 waves/block -> VGPR~110
//  fits 128 budget -> 4 waves/SIMD (2x TLP); (2) asm "+v" residency force —
//  compiler cannot rematerialize from memory.]
// Wave w owns cands [1024w,1024(w+1)); lane owns c[s]=cb[w*1024+s*64+lane]
// (coalesced). 64 queries/block from 1KB LDS table.
//  A: dual-chain lane max over 16 -> shfl_xor(1,2,4) 8-lane reduce -> 64
//     submaxima (disjoint 128-cand groups) covering all 8192.
//  T: tau = 16th largest of 64 submaxima (r9-validated bitonic, no padding)
//     -> >=16 witnesses >= tau guaranteed.
//  B: re-score (bit-identical fma, c resident), ballot-prefix push.
//  S: thread-per-query u64 sorted-insert over 8 wave-lists -> idxb.
// Grid: NQ/64 = 512 blocks x 512 threads.
// ---------------------------------------------------------------------------
__global__ __launch_bounds__(512, 4) void knn_fused3(
    const float4* __restrict__ cand, const float* __restrict__ xyz,
    int* __restrict__ idxout)
{
    __shared__ float4 qt_lds[64];
    __shared__ float  mxs[64][66];
    __shared__ float  tauL[64];
    __shared__ unsigned short wl[8][64][CAP3P];
    __shared__ unsigned char  wcnt[8][64];

    int tid = threadIdx.x;
    int lane = tid & 63, w = tid >> 6;     // w in 0..7
    int bid = blockIdx.x;
    int b = bid >> 7;                      // 128 blocks per batch
    int qb = (bid & 127) * 64;

    if (tid < 64) {
        int q = qb + tid;
        float x = xyz[(b * 3 + 0) * NPTS + q];
        float y = xyz[(b * 3 + 1) * NPTS + q];
        float z = xyz[(b * 3 + 2) * NPTS + q];
        qt_lds[tid] = make_float4(2.f * x, 2.f * y, 2.f * z, 0.f);
    }

    const float4* cb = cand + b * NPTS;
    int cbase = (w << 10) + lane;          // lane's cands: cbase + s*64
    float4 c[16];
    #pragma unroll
    for (int s = 0; s < 16; s++) c[s] = cb[cbase + (s << 6)];
    // residency force: values now opaque — compiler cannot re-load from mem
    #pragma unroll
    for (int s = 0; s < 16; s++)
        asm volatile("" : "+v"(c[s].x), "+v"(c[s].y), "+v"(c[s].z), "+v"(c[s].w));
    __syncthreads();

    // ---- A: 64 submaxima per query (dual-chain lane max + 8-lane reduce) --
    for (int qi = 0; qi < 64; ++qi) {
        float4 qt = qt_lds[qi];
        float M0 = -3.0e38f, M1 = -3.0e38f;
        #pragma unroll
        for (int s = 0; s < 16; s += 2) {
            float sc0 = fmaf(c[s].x, qt.x, fmaf(c[s].y, qt.y,
                        fmaf(c[s].z, qt.z, -c[s].w)));
            float sc1 = fmaf(c[s+1].x, qt.x, fmaf(c[s+1].y, qt.y,
                        fmaf(c[s+1].z, qt.z, -c[s+1].w)));
            M0 = fmaxf(M0, sc0);
            M1 = fmaxf(M1, sc1);
        }
        float gmx = fmaxf(M0, M1);
        gmx = fmaxf(gmx, __shfl_xor(gmx, 1));
        gmx = fmaxf(gmx, __shfl_xor(gmx, 2));
        gmx = fmaxf(gmx, __shfl_xor(gmx, 4));   // 8-lane group max
        if ((lane & 7) == 0) mxs[qi][(w << 3) + (lane >> 3)] = gmx;
    }
    __syncthreads();

    // ---- T: tau = 16th largest of 64 submaxima (bitonic, all lanes) ----
    for (int qq = w * 8; qq < w * 8 + 8; ++qq) {
        float v = mxs[qq][lane];
        #pragma unroll
        for (int k = 2; k <= 64; k <<= 1) {
            #pragma unroll
            for (int j = k >> 1; j > 0; j >>= 1) {
                float o = __shfl_xor(v, j);
                bool up = ((lane & k) == 0);
                bool lower = ((lane & j) == 0);
                v = (up == lower) ? fminf(v, o) : fmaxf(v, o);
            }
        }
        float t = __shfl(v, 48);           // 16th largest (all lanes execute)
        if (lane == 0) tauL[qq] = t;
    }
    __syncthreads();

    // ---- B: filter with ballot-prefix push (zero atomics, c resident) ----
    unsigned long long lmask = (1ull << lane) - 1ull;
    for (int qi = 0; qi < 64; ++qi) {
        float4 qt = qt_lds[qi];
        float tau = tauL[qi];
        unsigned vcnt = 0;
        #pragma unroll
        for (int s = 0; s < 16; s++) {
            float sc = fmaf(c[s].x, qt.x, fmaf(c[s].y, qt.y,
                       fmaf(c[s].z, qt.z, -c[s].w)));
            bool p = (sc >= tau);
            unsigned long long mask = __ballot(p);
            if (p) {
                unsigned pos = vcnt + (unsigned)__popcll(mask & lmask);
                if (pos < CAP3)
                    wl[w][qi][pos] = (unsigned short)(cbase + (s << 6));
            }
            vcnt += (unsigned)__popcll(mask);
        }
        if (lane == 0)
            wcnt[w][qi] = (unsigned char)(vcnt < CAP3 ? vcnt : CAP3);
    }
    __syncthreads();

    // ---- S: thread-per-query top-16 select (r7/r12-validated insert) ----
    if (tid < 64) {
        int qi = tid;
        float4 qt = qt_lds[qi];
        unsigned long long s16[KNN];
        #pragma unroll
        for (int j = 0; j < KNN; j++) s16[j] = 0ull;

        for (int cgp = 0; cgp < 8; cgp++) {
            int cn = wcnt[cgp][qi];
            for (int j0 = 0; j0 < cn; j0 += 4) {
                int li[4];
                float4 cd[4];
                #pragma unroll
                for (int t = 0; t < 4; t++) {
                    int j = j0 + t;
                    li[t] = (j < cn) ? (int)wl[cgp][qi][j] : -1;
                }
                #pragma unroll
                for (int t = 0; t < 4; t++)
                    if (li[t] >= 0) cd[t] = cb[li[t]];
                #pragma unroll
                for (int t = 0; t < 4; t++) {
                    if (li[t] < 0) continue;
                    float sc = fmaf(cd[t].x, qt.x, fmaf(cd[t].y, qt.y,
                               fmaf(cd[t].z, qt.z, -cd[t].w)));
                    unsigned u = __float_as_uint(sc);
                    u ^= (unsigned)((int)u >> 31) | 0x80000000u;
                    unsigned long long key =
                        ((unsigned long long)u << 32) | (unsigned)(8191 - li[t]);
                    if (key > s16[0]) {
                        bool cj = true;
                        #pragma unroll
                        for (int t2 = 0; t2 < KNN; t2++) {
                            bool cn2 = (t2 < KNN - 1) ? (key > s16[t2 + 1]) : false;
                            unsigned long long fv = cj ? key : s16[t2];
                            s16[t2] = cn2 ? s16[t2 + 1] : fv;
                            cj = cn2;
                        }
                    }
                }
            }
        }
        int* op = idxout + (((size_t)(b * NPTS + qb + qi)) << 4);
        #pragma unroll
        for (int j = 0; j < KNN; j++)
            op[j] = 8191 - (int)(s16[j] & 0xFFFFFFFFull);
    }
}

// ---------------------------------------------------------------------------
// fuse — unchanged (validated r2..r14):
// out[b][o][n] = max_k relu(CF.x + wd*d + GF.x) * relu(CF.y + GF.y)
// ---------------------------------------------------------------------------
__global__ __launch_bounds__(256) void fuse_kernel(
    const float* __restrict__ xyz, const float* __restrict__ Wg,
    const float4* __restrict__ cand, const float2* __restrict__ GF,
    const float2* __restrict__ CF, const int* __restrict__ idxb,
    float* __restrict__ out)
{
    __shared__ float tile[16 * 65];
    int tid = threadIdx.x;
    int o = tid & 63, w = tid >> 6;
    int b = blockIdx.x >> 9;
    int nt = (blockIdx.x & 511) << 4;
    float wd = Wg[o * 10];

    for (int i = 0; i < 4; i++) {
        int q = nt + w * 4 + i;
        size_t qb = (size_t)(b * NPTS + q);
        float qx = xyz[(b * 3 + 0) * NPTS + q];
        float qy = xyz[(b * 3 + 1) * NPTS + q];
        float qz = xyz[(b * 3 + 2) * NPTS + q];
        float2 cf = CF[qb * NC + o];
        const int* ip = idxb + qb * KNN;
        float r = 0.f;
        #pragma unroll 4
        for (int kk = 0; kk < KNN; kk++) {
            int mi = ip[kk];
            float4 c = cand[b * NPTS + mi];
            float dx = qx - c.x, dy = qy - c.y, dz = qz - c.z;
            float d = sqrtf(fmaf(dx, dx, fmaf(dy, dy, dz * dz)));
            float2 gf = GF[((size_t)(b * NPTS + mi)) * NC + o];
            float gpre = cf.x + fmaf(wd, d, gf.x);
            float fpre = cf.y + gf.y;
            r = fmaxf(r, fmaxf(gpre, 0.f) * fmaxf(fpre, 0.f));
        }
        tile[(w * 4 + i) * 65 + o] = r;
    }
    __syncthreads();
    int row = tid >> 2, cg = (tid & 3) * 4;
    float* orow = out + (size_t)(b * NC + row) * NPTS + nt + cg;
    #pragma unroll
    for (int j = 0; j < 4; j++) orow[j] = tile[(cg + j) * 65 + row];
}

extern "C" void kernel_launch(void* const* d_in, const int* in_sizes, int n_in,
                              void* d_out, int out_size, void* d_ws, size_t ws_size,
                              hipStream_t stream) {
    const float* xyz   = (const float*)d_in[0];
    const float* xyz_s = (const float*)d_in[1];
    const float* fea   = (const float*)d_in[2];
    const float* fea_s = (const float*)d_in[3];
    const float* Wg    = (const float*)d_in[4];
    const float* bg    = (const float*)d_in[5];
    const float* Wf    = (const float*)d_in[6];
    const float* bf    = (const float*)d_in[7];
    float* out = (float*)d_out;

    char* ws = (char*)d_ws;
    float4* cand = (float4*)ws;                 ws += (size_t)NQ * 16;      // 512 KB
    float2* GF   = (float2*)ws;                 ws += (size_t)NQ * NC * 8;  // 16.8 MB
    float2* CF   = (float2*)ws;                 ws += (size_t)NQ * NC * 8;  // 16.8 MB
    int*    idxb = (int*)ws;                                                // 2 MB

    prep_kernel<<<(NQ / 256) * 2, 256, 0, stream>>>(
        xyz, xyz_s, fea, fea_s, Wg, bg, Wf, bf, cand, GF, CF);
    knn_fused3<<<NQ / 64, 512, 0, stream>>>(cand, xyz, idxb);
    fuse_kernel<<<NB * (NPTS / 16), 256, 0, stream>>>(
        xyz, Wg, cand, GF, CF, idxb, out);
}

// Round 16
// 197.251 us; speedup vs baseline: 1.2861x; 1.0519x over previous
//
#include <hip/hip_runtime.h>
#include <math.h>

#define NPTS 8192
#define NB   4
#define KNN  16
#define NC   64
#define NQ   (NB * NPTS)   // 32768 total queries
#define ECAP 20            // per-(wave,query) packed-entry capacity (E~2.7)
#define ILCAP 66           // per-query decoded survivor idx capacity (E~22)

// ---------------------------------------------------------------------------
// prep (2 phases as separate blocks) — unchanged (validated r2..r15):
//  phase 0 (source pts): cand[b][m]=(x,y,z,|p|^2); GF[b][m][o]=(Gk,F2)
//  phase 1 (center pts): CF[b][n][o]=(Gc+bg, F1+bf)
// ---------------------------------------------------------------------------
__global__ __launch_bounds__(256) void prep_kernel(
    const float* __restrict__ xyz, const float* __restrict__ xyz_s,
    const float* __restrict__ fea, const float* __restrict__ fea_s,
    const float* __restrict__ Wg,  const float* __restrict__ bg,
    const float* __restrict__ Wf,  const float* __restrict__ bf,
    float4* __restrict__ cand, float2* __restrict__ GF, float2* __restrict__ CF)
{
    __shared__ float wt[64 * 64];
    __shared__ float gw[3 * 64];
    __shared__ float bias2[2 * 64];
    int tid   = threadIdx.x;
    int phase = blockIdx.x & 1;
    int g     = (blockIdx.x >> 1) * 256 + tid;
    int b     = g >> 13, m = g & (NPTS - 1);

    for (int i = tid; i < 4096; i += 256) {
        int o = i >> 6, c = i & 63;
        wt[c * 64 + o] = Wf[o * 128 + (phase ? c : 64 + c)];
    }
    if (tid < 192) {
        int d = tid >> 6, o = tid & 63;
        gw[d * 64 + o] = phase ? (Wg[o * 10 + 1 + d] + Wg[o * 10 + 7 + d])
                               : (Wg[o * 10 + 4 + d] - Wg[o * 10 + 7 + d]);
    }
    if (tid < 64) {
        bias2[tid]      = phase ? bg[tid] : 0.f;
        bias2[64 + tid] = phase ? bf[tid] : 0.f;
    }
    __syncthreads();

    const float* P = phase ? xyz : xyz_s;
    const float* F = phase ? fea : fea_s;
    float x = P[(b * 3 + 0) * NPTS + m];
    float y = P[(b * 3 + 1) * NPTS + m];
    float z = P[(b * 3 + 2) * NPTS + m];
    if (!phase) cand[b * NPTS + m] = make_float4(x, y, z, x * x + y * y + z * z);

    float acc[NC];
    #pragma unroll
    for (int o = 0; o < NC; o++) acc[o] = 0.f;
    for (int c = 0; c < NC; c++) {
        float v = F[(size_t)(b * NC + c) * NPTS + m];
        const float4* w4 = (const float4*)&wt[c * 64];
        #pragma unroll
        for (int o4 = 0; o4 < 16; o4++) {
            float4 w = w4[o4];
            acc[o4*4+0] = fmaf(w.x, v, acc[o4*4+0]);
            acc[o4*4+1] = fmaf(w.y, v, acc[o4*4+1]);
            acc[o4*4+2] = fmaf(w.z, v, acc[o4*4+2]);
            acc[o4*4+3] = fmaf(w.w, v, acc[o4*4+3]);
        }
    }
    float2* O = (phase ? CF : GF) + ((size_t)(b * NPTS + m)) * NC;
    #pragma unroll
    for (int o = 0; o < NC; o++) {
        float geo = fmaf(gw[o], x, fmaf(gw[64 + o], y, gw[128 + o] * z));
        O[o] = make_float2(geo + bias2[o], acc[o] + bias2[64 + o]);
    }
}

// ---------------------------------------------------------------------------
// knn_fused4: tau + filter + select, candidate-stationary, 8 waves/block.
// [r15 post-mortem: B-phase per-candidate __ballot+popcll = ~6 extra ops AND
//  a vcc->sgpr->vgpr serialization per candidate (1024/wave) — the VALUBusy-
//  65% cap. Fix: branch-free per-lane u16 survivor MASK (cmp+cndmask+or, no
//  cross-lane), ONE ballot per (wave,query) pushing packed (lane<<16)|mask
//  entries; select decodes entries into an idx list (reusing dead mxs LDS)
//  then runs the validated batch-4 gather + u64 insert.]
// Wave w owns cands [1024w,1024(w+1)); lane owns c[s]=cb[w*1024+s*64+lane].
//  A: dual-chain lane max -> shfl_xor(1,2,4) -> 64 submaxima (128-cand
//     disjoint groups covering all 8192).
//  T: tau = 16th largest of 64 submaxima (r9-validated bitonic); stored in
//     qt_lds[q].w (A never reads .w). >=16 witnesses guaranteed.
//  B: mask filter (bit-identical fma score), packed-entry push (1 ballot/q).
//  S: decode -> idx list -> r15-validated u64 sorted-insert -> idxb.
// Grid: NQ/64 = 512 blocks x 512 threads.
// ---------------------------------------------------------------------------
__global__ __launch_bounds__(512, 4) void knn_fused4(
    const float4* __restrict__ cand, const float* __restrict__ xyz,
    int* __restrict__ idxout)
{
    __shared__ float4 qt_lds[64];            // .w = tau after T
    __shared__ float  mxs[64][ILCAP];        // A/T: submaxima; S: idx list
    __shared__ unsigned int  el[8][64][ECAP];
    __shared__ unsigned char ecnt[8][64];

    int tid = threadIdx.x;
    int lane = tid & 63, w = tid >> 6;       // w in 0..7
    int bid = blockIdx.x;
    int b = bid >> 7;                        // 128 blocks per batch
    int qb = (bid & 127) * 64;

    if (tid < 64) {
        int q = qb + tid;
        float x = xyz[(b * 3 + 0) * NPTS + q];
        float y = xyz[(b * 3 + 1) * NPTS + q];
        float z = xyz[(b * 3 + 2) * NPTS + q];
        qt_lds[tid] = make_float4(2.f * x, 2.f * y, 2.f * z, 0.f);
    }

    const float4* cb = cand + b * NPTS;
    int cbase = (w << 10) + lane;            // lane's cands: cbase + s*64
    float4 c[16];
    #pragma unroll
    for (int s = 0; s < 16; s++) c[s] = cb[cbase + (s << 6)];
    // residency force (r15-validated): compiler cannot re-load from memory
    #pragma unroll
    for (int s = 0; s < 16; s++)
        asm volatile("" : "+v"(c[s].x), "+v"(c[s].y), "+v"(c[s].z), "+v"(c[s].w));
    __syncthreads();

    // ---- A: 64 submaxima per query (dual-chain lane max + 8-lane reduce) --
    for (int qi = 0; qi < 64; ++qi) {
        float4 qt = qt_lds[qi];
        float M0 = -3.0e38f, M1 = -3.0e38f;
        #pragma unroll
        for (int s = 0; s < 16; s += 2) {
            float sc0 = fmaf(c[s].x, qt.x, fmaf(c[s].y, qt.y,
                        fmaf(c[s].z, qt.z, -c[s].w)));
            float sc1 = fmaf(c[s+1].x, qt.x, fmaf(c[s+1].y, qt.y,
                        fmaf(c[s+1].z, qt.z, -c[s+1].w)));
            M0 = fmaxf(M0, sc0);
            M1 = fmaxf(M1, sc1);
        }
        float gmx = fmaxf(M0, M1);
        gmx = fmaxf(gmx, __shfl_xor(gmx, 1));
        gmx = fmaxf(gmx, __shfl_xor(gmx, 2));
        gmx = fmaxf(gmx, __shfl_xor(gmx, 4));   // 8-lane group max
        if ((lane & 7) == 0) mxs[qi][(w << 3) + (lane >> 3)] = gmx;
    }
    __syncthreads();

    // ---- T: tau = 16th largest of 64 submaxima -> qt_lds[qq].w ----
    for (int qq = w * 8; qq < w * 8 + 8; ++qq) {
        float v = mxs[qq][lane];
        #pragma unroll
        for (int k = 2; k <= 64; k <<= 1) {
            #pragma unroll
            for (int j = k >> 1; j > 0; j >>= 1) {
                float o = __shfl_xor(v, j);
                bool up = ((lane & k) == 0);
                bool lower = ((lane & j) == 0);
                v = (up == lower) ? fminf(v, o) : fmaxf(v, o);
            }
        }
        float t = __shfl(v, 48);             // 16th largest (all lanes)
        if (lane == 0) qt_lds[qq].w = t;
    }
    __syncthreads();

    // ---- B: branch-free mask filter; ONE ballot per (wave,query) ----
    unsigned long long lmask = (1ull << lane) - 1ull;
    for (int qi = 0; qi < 64; ++qi) {
        float4 qt = qt_lds[qi];              // .w = tau
        unsigned msk = 0;
        #pragma unroll
        for (int s = 0; s < 16; s++) {
            float sc = fmaf(c[s].x, qt.x, fmaf(c[s].y, qt.y,
                       fmaf(c[s].z, qt.z, -c[s].w)));
            msk |= (sc >= qt.w) ? (1u << s) : 0u;
        }
        unsigned long long m = __ballot(msk != 0u);
        if (msk) {
            unsigned pos = (unsigned)__popcll(m & lmask);
            if (pos < ECAP)
                el[w][qi][pos] = ((unsigned)lane << 16) | msk;
        }
        if (lane == 0) {
            unsigned tot = (unsigned)__popcll(m);
            ecnt[w][qi] = (unsigned char)(tot < ECAP ? tot : ECAP);
        }
    }
    __syncthreads();

    // ---- S: decode entries -> idx list (reuse mxs row), then top-16 ----
    if (tid < 64) {
        int qi = tid;
        unsigned* il = (unsigned*)&mxs[qi][0];   // ILCAP u32 slots
        int cnt = 0;
        for (int w2 = 0; w2 < 8; w2++) {
            int cn = ecnt[w2][qi];
            for (int j = 0; j < cn; j++) {
                unsigned e = el[w2][qi][j];
                int base = (w2 << 10) + (int)(e >> 16);
                unsigned mk = e & 0xFFFFu;
                while (mk) {
                    int s = __builtin_ctz(mk);
                    mk &= mk - 1u;
                    if (cnt < ILCAP) il[cnt++] = (unsigned)(base + (s << 6));
                }
            }
        }

        float4 qt = qt_lds[qi];
        unsigned long long s16[KNN];
        #pragma unroll
        for (int j = 0; j < KNN; j++) s16[j] = 0ull;

        for (int j0 = 0; j0 < cnt; j0 += 4) {
            int li[4];
            float4 cd[4];
            #pragma unroll
            for (int t = 0; t < 4; t++) {
                int j = j0 + t;
                li[t] = (j < cnt) ? (int)il[j] : -1;
            }
            #pragma unroll
            for (int t = 0; t < 4; t++)
                if (li[t] >= 0) cd[t] = cb[li[t]];
            #pragma unroll
            for (int t = 0; t < 4; t++) {
                if (li[t] < 0) continue;
                float sc = fmaf(cd[t].x, qt.x, fmaf(cd[t].y, qt.y,
                           fmaf(cd[t].z, qt.z, -cd[t].w)));
                unsigned u = __float_as_uint(sc);
                u ^= (unsigned)((int)u >> 31) | 0x80000000u;
                unsigned long long key =
                    ((unsigned long long)u << 32) | (unsigned)(8191 - li[t]);
                if (key > s16[0]) {
                    bool cj = true;
                    #pragma unroll
                    for (int t2 = 0; t2 < KNN; t2++) {
                        bool cn2 = (t2 < KNN - 1) ? (key > s16[t2 + 1]) : false;
                        unsigned long long fv = cj ? key : s16[t2];
                        s16[t2] = cn2 ? s16[t2 + 1] : fv;
                        cj = cn2;
                    }
                }
            }
        }
        int* op = idxout + (((size_t)(b * NPTS + qb + qi)) << 4);
        #pragma unroll
        for (int j = 0; j < KNN; j++)
            op[j] = 8191 - (int)(s16[j] & 0xFFFFFFFFull);
    }
}

// ---------------------------------------------------------------------------
// fuse — unchanged (validated r2..r15):
// out[b][o][n] = max_k relu(CF.x + wd*d + GF.x) * relu(CF.y + GF.y)
// ---------------------------------------------------------------------------
__global__ __launch_bounds__(256) void fuse_kernel(
    const float* __restrict__ xyz, const float* __restrict__ Wg,
    const float4* __restrict__ cand, const float2* __restrict__ GF,
    const float2* __restrict__ CF, const int* __restrict__ idxb,
    float* __restrict__ out)
{
    __shared__ float tile[16 * 65];
    int tid = threadIdx.x;
    int o = tid & 63, w = tid >> 6;
    int b = blockIdx.x >> 9;
    int nt = (blockIdx.x & 511) << 4;
    float wd = Wg[o * 10];

    for (int i = 0; i < 4; i++) {
        int q = nt + w * 4 + i;
        size_t qb = (size_t)(b * NPTS + q);
        float qx = xyz[(b * 3 + 0) * NPTS + q];
        float qy = xyz[(b * 3 + 1) * NPTS + q];
        float qz = xyz[(b * 3 + 2) * NPTS + q];
        float2 cf = CF[qb * NC + o];
        const int* ip = idxb + qb * KNN;
        float r = 0.f;
        #pragma unroll 4
        for (int kk = 0; kk < KNN; kk++) {
            int mi = ip[kk];
            float4 c = cand[b * NPTS + mi];
            float dx = qx - c.x, dy = qy - c.y, dz = qz - c.z;
            float d = sqrtf(fmaf(dx, dx, fmaf(dy, dy, dz * dz)));
            float2 gf = GF[((size_t)(b * NPTS + mi)) * NC + o];
            float gpre = cf.x + fmaf(wd, d, gf.x);
            float fpre = cf.y + gf.y;
            r = fmaxf(r, fmaxf(gpre, 0.f) * fmaxf(fpre, 0.f));
        }
        tile[(w * 4 + i) * 65 + o] = r;
    }
    __syncthreads();
    int row = tid >> 2, cg = (tid & 3) * 4;
    float* orow = out + (size_t)(b * NC + row) * NPTS + nt + cg;
    #pragma unroll
    for (int j = 0; j < 4; j++) orow[j] = tile[(cg + j) * 65 + row];
}

extern "C" void kernel_launch(void* const* d_in, const int* in_sizes, int n_in,
                              void* d_out, int out_size, void* d_ws, size_t ws_size,
                              hipStream_t stream) {
    const float* xyz   = (const float*)d_in[0];
    const float* xyz_s = (const float*)d_in[1];
    const float* fea   = (const float*)d_in[2];
    const float* fea_s = (const float*)d_in[3];
    const float* Wg    = (const float*)d_in[4];
    const float* bg    = (const float*)d_in[5];
    const float* Wf    = (const float*)d_in[6];
    const float* bf    = (const float*)d_in[7];
    float* out = (float*)d_out;

    char* ws = (char*)d_ws;
    float4* cand = (float4*)ws;                 ws += (size_t)NQ * 16;      // 512 KB
    float2* GF   = (float2*)ws;                 ws += (size_t)NQ * NC * 8;  // 16.8 MB
    float2* CF   = (float2*)ws;                 ws += (size_t)NQ * NC * 8;  // 16.8 MB
    int*    idxb = (int*)ws;                                                // 2 MB

    prep_kernel<<<(NQ / 256) * 2, 256, 0, stream>>>(
        xyz, xyz_s, fea, fea_s, Wg, bg, Wf, bf, cand, GF, CF);
    knn_fused4<<<NQ / 64, 512, 0, stream>>>(cand, xyz, idxb);
    fuse_kernel<<<NB * (NPTS / 16), 256, 0, stream>>>(
        xyz, Wg, cand, GF, CF, idxb, out);
}